// Round 11
// baseline (339.240 us; speedup 1.0000x reference)
//
#include <hip/hip_runtime.h>
#include <hip/hip_bf16.h>
#include <hip/hip_cooperative_groups.h>

namespace cg = cooperative_groups;

#define BB 4
#define SEQ 2048
#define NH 4
#define D 64
#define HOUT 8
#define LOSS_BASE ((size_t)BB * SEQ * HOUT * D)

// ---- ws layout ----
// f32: part[4][16][3][4096] | Spart[16][32][64] | lpart[2][16][2048]
// ushort: 0 Khi, 1 VbfT, 2 Uhn, 3 Ehn, 4 valn, 5 Ughi, 6 Uglo (each 16*2048*64), then OpartUS[2][16][2048][64]
#define N_PART   (4 * 16 * 3 * 4096)
#define OFF_SPART N_PART
#define N_SPART  (16 * 32 * 64)
#define OFF_LPART (OFF_SPART + N_SPART)
#define N_LPART  (2 * 16 * 2048)
#define OFF_F32_END (OFF_LPART + N_LPART)
#define USZ ((size_t)16 * 2048 * 64)
#define PSTR 72
#define NBLK 576
#define SMEM_BYTES 36864

typedef __attribute__((ext_vector_type(8))) short bf16x8;
typedef __attribute__((ext_vector_type(4))) float f32x4;
typedef __attribute__((ext_vector_type(8))) unsigned short us8;
typedef __attribute__((ext_vector_type(4))) unsigned short us4;

struct Args {
    const float *U, *Sg, *Vagf, *vals, *Ksm, *Vsm, *gam, *Q;
    float *ws, *out;
};
struct WSP {
    float *part, *Spart, *lpart;
    unsigned short *Khi, *VbfT, *Uhn, *Ehn, *valn, *Ughi, *Uglo, *OpartUS;
};

__device__ __forceinline__ unsigned short f2bf(float x) {
    union { float f; unsigned u; } v; v.f = x;
    unsigned r = v.u + 0x7fffu + ((v.u >> 16) & 1u);
    return (unsigned short)(r >> 16);
}
__device__ __forceinline__ float bf2f(unsigned short u) {
    union { unsigned u; float f; } v; v.u = ((unsigned)u) << 16; return v.f;
}
__device__ __forceinline__ void load16(const float* p, float* v) {
    const float4* q = (const float4*)p;
    float4 a = q[0], b = q[1], c = q[2], d = q[3];
    v[0]=a.x; v[1]=a.y; v[2]=a.z; v[3]=a.w;
    v[4]=b.x; v[5]=b.y; v[6]=b.z; v[7]=b.w;
    v[8]=c.x; v[9]=c.y; v[10]=c.z; v[11]=c.w;
    v[12]=d.x; v[13]=d.y; v[14]=d.z; v[15]=d.w;
}
__device__ __forceinline__ void wr_bf16x16(unsigned short* dst, const float* v) {
    us8 w0, w1;
#pragma unroll
    for (int i = 0; i < 8; i++) { w0[i] = f2bf(v[i]); w1[i] = f2bf(v[8 + i]); }
    *(us8*)dst = w0; *(us8*)(dst + 8) = w1;
}
__device__ __forceinline__ WSP mkws(float* ws) {
    WSP w;
    w.part = ws; w.Spart = ws + OFF_SPART; w.lpart = ws + OFF_LPART;
    unsigned short* usb = (unsigned short*)(ws + OFF_F32_END);
    w.Khi = usb; w.VbfT = usb + USZ; w.Uhn = usb + 2 * USZ; w.Ehn = usb + 3 * USZ;
    w.valn = usb + 4 * USZ; w.Ughi = usb + 5 * USZ; w.Uglo = usb + 6 * USZ;
    w.OpartUS = usb + 7 * USZ;
    return w;
}

// ================= phase A: prep (bid 0..511) =================
__device__ void phase_prep(int bid, int tid, unsigned char* smem, const Args& a, const WSP& wsp) {
    int lt = bid & 31, p = bid >> 5;
    int b = p >> 2, h = p & 3;
    int r = tid >> 2;
    int c0 = (tid & 3) * 16;
    float (*T)[68] = (float(*)[68])smem;          // 17408 B
    float* redp = (float*)(smem + 17408);         // 1024 B
    const size_t gbase = ((size_t)(b * SEQ + lt * 64 + r) * NH + h) * D + c0;
    const size_t nbase = ((size_t)(p * SEQ + lt * 64 + r)) * 64 + c0;
    const size_t tbase = ((size_t)p * 64 + r) * 2048 + lt * 64 + c0;
    float v[16], e[16];

    // U -> row softmax -> Uhn natural + Ug hi/lo natural
    load16(a.U + gbase, v);
    float mx = v[0];
#pragma unroll
    for (int k = 1; k < 16; k++) mx = fmaxf(mx, v[k]);
    mx = fmaxf(mx, __shfl_xor(mx, 1));
    mx = fmaxf(mx, __shfl_xor(mx, 2));
    float sm = 0.0f;
#pragma unroll
    for (int k = 0; k < 16; k++) { v[k] = __expf(v[k] - mx); sm += v[k]; }
    sm += __shfl_xor(sm, 1);
    sm += __shfl_xor(sm, 2);
    float inv = 1.0f / sm;
#pragma unroll
    for (int k = 0; k < 16; k++) v[k] *= inv;
    wr_bf16x16(wsp.Uhn + nbase, v);
    {
        float sg[16];
        load16(a.Sg + gbase, sg);
        float g0 = a.gam[0], g1 = a.gam[1], g2 = a.gam[2], g3 = a.gam[3];
        us8 h0, h1, l0, l1;
#pragma unroll
        for (int k = 0; k < 16; k++) {
            float sig = 1.0f / (1.0f + __expf(-sg[k]));
            float x1 = 2.0f * sig;
            float x2 = 1.875f * sig * x1 - 0.75f;
            float x3 = 1.8666666666666667f * sig * x2 - 0.8f * x1;
            float ug = v[k] * (g0 + g1 * x1 + g2 * x2 + g3 * x3);
            unsigned short hh = f2bf(ug);
            unsigned short ll = f2bf(ug - bf2f(hh));
            if (k < 8) { h0[k] = hh; l0[k] = ll; } else { h1[k - 8] = hh; l1[k - 8] = ll; }
        }
        *(us8*)(wsp.Ughi + nbase) = h0; *(us8*)(wsp.Ughi + nbase + 8) = h1;
        *(us8*)(wsp.Uglo + nbase) = l0; *(us8*)(wsp.Uglo + nbase + 8) = l1;
    }

    // E = exp(Vagf) -> Ehn natural + column-sum partials
    load16(a.Vagf + gbase, v);
#pragma unroll
    for (int k = 0; k < 16; k++) { v[k] = __expf(v[k]); T[r][c0 + k] = v[k]; }
    wr_bf16x16(wsp.Ehn + nbase, v);
    __syncthreads();
    {
        int d = tid & 63, grp = tid >> 6;
        float s = 0.0f;
#pragma unroll
        for (int i = 0; i < 16; i++) s += T[grp * 16 + i][d];
        redp[grp * 64 + d] = s;
        __syncthreads();
        if (tid < 64)
            wsp.Spart[(p * 32 + lt) * 64 + tid] =
                redp[tid] + redp[64 + tid] + redp[128 + tid] + redp[192 + tid];
    }

    // vals -> valn natural
    load16(a.vals + gbase, v);
    wr_bf16x16(wsp.valn + nbase, v);

    // Vsm -> VbfT transposed (flash needs V^T)
    load16(a.Vsm + gbase, v);
    __syncthreads();
#pragma unroll
    for (int k = 0; k < 16; k++) T[r][c0 + k] = v[k];
    __syncthreads();
#pragma unroll
    for (int k = 0; k < 16; k++) e[k] = T[c0 + k][r];
    wr_bf16x16(wsp.VbfT + tbase, e);

    // K -> Khi natural
    load16(a.Ksm + gbase, v);
    wr_bf16x16(wsp.Khi + nbase, v);

    if (bid == 0 && tid < BB) a.out[LOSS_BASE + tid] = 0.0f;
}

// ================= phase B1: flash7 (fb 0..511) =================
__device__ void phase_flash(int fb, int tid, unsigned char* smem, const Args& a, const WSP& wsp) {
    const int w = tid >> 6, lane = tid & 63, lm = lane & 15, quad = lane >> 4;
    int qt2 = fb & 15, p = (fb >> 4) & 15, half = fb >> 8;
    int b = p >> 2, h = p & 3;
    unsigned short* Kl = (unsigned short*)smem;       // 9216
    unsigned short* Vl = Kl + 64 * PSTR;              // 9216
    unsigned short* Ph = Vl + 64 * PSTR;              // 18432
    const int srow = tid >> 2, sseg = (tid & 3) * 16;

    bf16x8 qhi[2][2], qlo[2][2];
#pragma unroll
    for (int q = 0; q < 2; q++) {
        int row = qt2 * 128 + q * 64 + w * 16 + lm;
        const float* qp = a.Q + ((size_t)(b * SEQ + row) * NH + h) * D + quad * 8;
#pragma unroll
        for (int ks = 0; ks < 2; ks++) {
            float qq[8];
            float4 a0 = *(const float4*)(qp + ks * 32);
            float4 a1 = *(const float4*)(qp + ks * 32 + 4);
            qq[0]=a0.x; qq[1]=a0.y; qq[2]=a0.z; qq[3]=a0.w;
            qq[4]=a1.x; qq[5]=a1.y; qq[6]=a1.z; qq[7]=a1.w;
#pragma unroll
            for (int j = 0; j < 8; j++) {
                float xs = qq[j] * 0.125f;
                unsigned short hi = f2bf(xs);
                qhi[q][ks][j] = (short)hi;
                qlo[q][ks][j] = (short)f2bf(xs - bf2f(hi));
            }
        }
    }

    float rsum[2] = {0.f, 0.f};
    f32x4 o[2][4];
#pragma unroll
    for (int q = 0; q < 2; q++)
#pragma unroll
        for (int t = 0; t < 4; t++) o[q][t] = (f32x4){0.f, 0.f, 0.f, 0.f};

    for (int kt = 0; kt < 16; ++kt) {
        __syncthreads();
        {
            size_t kb = ((size_t)(p * SEQ + half * 1024 + kt * 64 + srow)) * 64 + sseg;
            us8 k0 = *(const us8*)(wsp.Khi + kb);
            us8 k1 = *(const us8*)(wsp.Khi + kb + 8);
            size_t vb = ((size_t)p * 64 + srow) * 2048 + half * 1024 + kt * 64 + sseg;
            us8 v0 = *(const us8*)(wsp.VbfT + vb);
            us8 v1 = *(const us8*)(wsp.VbfT + vb + 8);
            *(us8*)&Kl[srow * PSTR + sseg] = k0; *(us8*)&Kl[srow * PSTR + sseg + 8] = k1;
            *(us8*)&Vl[srow * PSTR + sseg] = v0; *(us8*)&Vl[srow * PSTR + sseg + 8] = v1;
        }
        __syncthreads();

        bf16x8 kfr[4][2], vfr[4][2];
#pragma unroll
        for (int t = 0; t < 4; t++)
#pragma unroll
            for (int ks = 0; ks < 2; ks++) {
                kfr[t][ks] = *(const bf16x8*)&Kl[(t * 16 + lm) * PSTR + ks * 32 + quad * 8];
                vfr[t][ks] = *(const bf16x8*)&Vl[(t * 16 + lm) * PSTR + ks * 32 + quad * 8];
            }

#pragma unroll
        for (int q = 0; q < 2; q++) {
            unsigned short* Phq = Ph + (size_t)(w * 2 + q) * 16 * PSTR;
            f32x4 s[4];
#pragma unroll
            for (int t = 0; t < 4; t++) s[t] = (f32x4){0.f, 0.f, 0.f, 0.f};
#pragma unroll
            for (int t = 0; t < 4; t++)
#pragma unroll
                for (int ks = 0; ks < 2; ks++) {
                    s[t] = __builtin_amdgcn_mfma_f32_16x16x32_bf16(kfr[t][ks], qhi[q][ks], s[t], 0, 0, 0);
                    s[t] = __builtin_amdgcn_mfma_f32_16x16x32_bf16(kfr[t][ks], qlo[q][ks], s[t], 0, 0, 0);
                }
#pragma unroll
            for (int t = 0; t < 4; t++) {
                float e0 = __expf(s[t][0]);
                float e1 = __expf(s[t][1]);
                float e2 = __expf(s[t][2]);
                float e3 = __expf(s[t][3]);
                rsum[q] += (e0 + e1) + (e2 + e3);
                us4 pk;
                pk[0] = f2bf(e0); pk[1] = f2bf(e1); pk[2] = f2bf(e2); pk[3] = f2bf(e3);
                *(us4*)&Phq[lm * PSTR + t * 16 + quad * 4] = pk;
            }
            bf16x8 pf0 = *(const bf16x8*)&Phq[lm * PSTR + quad * 8];
            bf16x8 pf1 = *(const bf16x8*)&Phq[lm * PSTR + 32 + quad * 8];
#pragma unroll
            for (int dt = 0; dt < 4; dt++) {
                o[q][dt] = __builtin_amdgcn_mfma_f32_16x16x32_bf16(vfr[dt][0], pf0, o[q][dt], 0, 0, 0);
                o[q][dt] = __builtin_amdgcn_mfma_f32_16x16x32_bf16(vfr[dt][1], pf1, o[q][dt], 0, 0, 0);
            }
        }
    }

#pragma unroll
    for (int q = 0; q < 2; q++) {
        float rs = rsum[q];
        rs += __shfl_xor(rs, 16);
        rs += __shfl_xor(rs, 32);
        int qrow = qt2 * 128 + q * 64 + w * 16 + lm;
        size_t ob = ((size_t)(half * 16 + p) * SEQ + qrow) * 64;
#pragma unroll
        for (int dt = 0; dt < 4; dt++) {
            us4 pk;
#pragma unroll
            for (int r = 0; r < 4; r++) pk[r] = f2bf(o[q][dt][r]);
            *(us4*)(wsp.OpartUS + ob + dt * 16 + quad * 4) = pk;
        }
        if (quad == 0) wsp.lpart[(size_t)(half * 16 + p) * SEQ + qrow] = rs;
    }
}

// ================= phase B2: gram with in-LDS transpose (g 0..63) =================
__device__ void phase_gram(int g, int tid, unsigned char* smem, const Args& a, const WSP& wsp) {
    const int w = tid >> 6, lane = tid & 63, lm = lane & 15, quad = lane >> 4;
    int split = g >> 4, p = g & 15;
    unsigned short* Ut = (unsigned short*)smem;       // 9216 each
    unsigned short* Eh = Ut + 64 * PSTR;
    unsigned short* Vt = Eh + 64 * PSTR;
    f32x4 su[4], sv[4], kv[4];
#pragma unroll
    for (int i = 0; i < 4; i++) { su[i] = (f32x4){0,0,0,0}; sv[i] = (f32x4){0,0,0,0}; kv[i] = (f32x4){0,0,0,0}; }
    int r0 = (tid & 15) * 4;     // l sub-offset
    int c0t = (tid >> 4) * 4;    // d sub-offset

    for (int step = 0; step < 8; ++step) {
        int l0 = split * 512 + step * 64;
        __syncthreads();
        {
            const unsigned short* srcs[3] = {wsp.Uhn, wsp.Ehn, wsp.valn};
            unsigned short* dsts[3] = {Ut, Eh, Vt};
#pragma unroll
            for (int ai = 0; ai < 3; ai++) {
                us4 rowv[4];
#pragma unroll
                for (int i = 0; i < 4; i++)
                    rowv[i] = *(const us4*)(srcs[ai] + ((size_t)p * 2048 + l0 + r0 + i) * 64 + c0t);
#pragma unroll
                for (int c = 0; c < 4; c++) {
                    us4 col;
#pragma unroll
                    for (int i = 0; i < 4; i++) col[i] = rowv[i][c];
                    *(us4*)&dsts[ai][(c0t + c) * PSTR + r0] = col;
                }
            }
        }
        __syncthreads();
#pragma unroll
        for (int ks = 0; ks < 2; ks++) {
            int ao = (w * 16 + lm) * PSTR + ks * 32 + quad * 8;
            bf16x8 au  = *(const bf16x8*)&Ut[ao];
            bf16x8 aeh = *(const bf16x8*)&Eh[ao];
#pragma unroll
            for (int nt = 0; nt < 4; nt++) {
                int bo = (nt * 16 + lm) * PSTR + ks * 32 + quad * 8;
                bf16x8 bu  = *(const bf16x8*)&Ut[bo];
                bf16x8 beh = *(const bf16x8*)&Eh[bo];
                bf16x8 bv  = *(const bf16x8*)&Vt[bo];
                su[nt] = __builtin_amdgcn_mfma_f32_16x16x32_bf16(au,  bu,  su[nt], 0, 0, 0);
                sv[nt] = __builtin_amdgcn_mfma_f32_16x16x32_bf16(aeh, beh, sv[nt], 0, 0, 0);
                kv[nt] = __builtin_amdgcn_mfma_f32_16x16x32_bf16(aeh, bv,  kv[nt], 0, 0, 0);
            }
        }
    }
    float* dst = wsp.part + (size_t)(split * 16 + p) * 3 * 4096;
#pragma unroll
    for (int nt = 0; nt < 4; nt++)
#pragma unroll
        for (int reg = 0; reg < 4; reg++) {
            int off = (w * 16 + quad * 4 + reg) * 64 + nt * 16 + lm;
            dst[off] = su[nt][reg];
            dst[4096 + off] = sv[nt][reg];
            dst[8192 + off] = kv[nt][reg];
        }
}

// ================= phase C: smerge stripes + agf + ortho =================
__device__ void phase_post(int bid, int tid, unsigned char* smem, const Args& a, const WSP& wsp) {
#pragma unroll
    for (int k = 0; k < 4; k++) {
        int slice = bid + k * NBLK;
        if (slice < 2048) {
            int idx = slice * 256 + tid;
            int p = idx >> 15;
            int rem = idx & 32767;
            int l = rem >> 4, dq = rem & 15;
            int b = p >> 2, h = p & 3;
            us4 x = *(const us4*)(wsp.OpartUS + ((size_t)p * SEQ + l) * 64 + dq * 4);
            us4 y = *(const us4*)(wsp.OpartUS + ((size_t)(16 + p) * SEQ + l) * 64 + dq * 4);
            float inv = 1.0f / (wsp.lpart[(size_t)p * SEQ + l] + wsp.lpart[(size_t)(16 + p) * SEQ + l]);
            f32x4 res;
#pragma unroll
            for (int r = 0; r < 4; r++) res[r] = (bf2f(x[r]) + bf2f(y[r])) * inv;
            *(f32x4*)(a.out + ((size_t)(b * SEQ + l) * HOUT + 4 + h) * D + dq * 4) = res;
        }
    }
    if (bid >= 528) return;
    const int w = tid >> 6, lane = tid & 63, lm = lane & 15, quad = lane >> 4;
    int p = (bid < 512) ? (bid >> 5) : (bid - 512);
    float* cis = (float*)smem;                                  // 256 B
    float* redp = (float*)(smem + 256);                         // 1024 B
    unsigned short* KVh = (unsigned short*)(smem + 1280);       // 9216
    unsigned short* KVl = (unsigned short*)(smem + 1280 + 64 * PSTR * 2);
    {
        int d = tid & 63, grp = tid >> 6;
        float s = 0.0f;
#pragma unroll
        for (int i = 0; i < 8; i++) s += wsp.Spart[(p * 32 + grp * 8 + i) * 64 + d];
        redp[grp * 64 + d] = s;
        __syncthreads();
        if (tid < 64) cis[tid] = 1.0f / (redp[tid] + redp[64 + tid] + redp[128 + tid] + redp[192 + tid]);
        __syncthreads();
    }
    if (bid >= 512) {
        float s = 0.0f;
        for (int idx = tid; idx < 8192; idx += 256) {
            int g = idx >> 12, i = idx & 4095;
            float v = 0.0f;
#pragma unroll
            for (int sp = 0; sp < 4; sp++) v += wsp.part[((size_t)(sp * 16 + p) * 3 + g) * 4096 + i];
            if (g) v *= cis[i >> 6] * cis[i & 63];
            float dg = ((i >> 6) == (i & 63)) ? 1.0f : 0.0f;
            s += fabsf(v - dg);
        }
#pragma unroll
        for (int o = 32; o > 0; o >>= 1) s += __shfl_xor(s, o);
        __syncthreads();
        if ((tid & 63) == 0) redp[tid >> 6] = s;
        __syncthreads();
        if (tid == 0)
            atomicAdd(&a.out[LOSS_BASE + (p >> 2)],
                      (redp[0] + redp[1] + redp[2] + redp[3]) * (1.0f / 16384.0f));
        return;
    }
    // agf: out = Ug @ KV (3-pass bf16 MFMA)
    int lt = bid & 31;
    int b = p >> 2, h = p & 3;
    for (int idx = tid; idx < 4096; idx += 256) {
        int d = idx >> 6, e = idx & 63;
        float v = 0.0f;
#pragma unroll
        for (int sp = 0; sp < 4; sp++) v += wsp.part[((size_t)(sp * 16 + p) * 3 + 2) * 4096 + idx];
        v *= cis[d];
        unsigned short hh = f2bf(v);
        KVh[e * PSTR + d] = hh;
        KVl[e * PSTR + d] = f2bf(v - bf2f(hh));
    }
    __syncthreads();
    size_t ub = ((size_t)(p * SEQ + lt * 64 + w * 16 + lm)) * 64 + quad * 8;
    bf16x8 ah[2], al[2];
#pragma unroll
    for (int ks = 0; ks < 2; ks++) {
        ah[ks] = *(const bf16x8*)(wsp.Ughi + ub + ks * 32);
        al[ks] = *(const bf16x8*)(wsp.Uglo + ub + ks * 32);
    }
    f32x4 acc[4];
#pragma unroll
    for (int nt = 0; nt < 4; nt++) acc[nt] = (f32x4){0.f, 0.f, 0.f, 0.f};
#pragma unroll
    for (int nt = 0; nt < 4; nt++)
#pragma unroll
        for (int ks = 0; ks < 2; ks++) {
            bf16x8 bh = *(const bf16x8*)&KVh[(nt * 16 + lm) * PSTR + ks * 32 + quad * 8];
            bf16x8 bl = *(const bf16x8*)&KVl[(nt * 16 + lm) * PSTR + ks * 32 + quad * 8];
            acc[nt] = __builtin_amdgcn_mfma_f32_16x16x32_bf16(ah[ks], bh, acc[nt], 0, 0, 0);
            acc[nt] = __builtin_amdgcn_mfma_f32_16x16x32_bf16(al[ks], bh, acc[nt], 0, 0, 0);
            acc[nt] = __builtin_amdgcn_mfma_f32_16x16x32_bf16(ah[ks], bl, acc[nt], 0, 0, 0);
        }
#pragma unroll
    for (int nt = 0; nt < 4; nt++)
#pragma unroll
        for (int reg = 0; reg < 4; reg++)
            a.out[((size_t)(b * SEQ + lt * 64 + w * 16 + quad * 4 + reg) * HOUT + h) * D + nt * 16 + lm] =
                acc[nt][reg];
}

// ================= cooperative fused kernel =================
__global__ __launch_bounds__(256, 3) void fused(Args a) {
    __shared__ __align__(16) unsigned char smem[SMEM_BYTES];
    const int bid = blockIdx.x, tid = threadIdx.x;
    WSP wsp = mkws(a.ws);
    if (bid < 512) phase_prep(bid, tid, smem, a, wsp);
    cg::this_grid().sync();
    if (bid < 512) phase_flash(bid, tid, smem, a, wsp);
    else phase_gram(bid - 512, tid, smem, a, wsp);
    cg::this_grid().sync();
    phase_post(bid, tid, smem, a, wsp);
}

// ================= fallback kernels (identical math) =================
__global__ __launch_bounds__(256, 3) void prep_k(Args a) {
    __shared__ __align__(16) unsigned char smem[SMEM_BYTES];
    WSP wsp = mkws(a.ws);
    phase_prep(blockIdx.x, threadIdx.x, smem, a, wsp);
}
__global__ __launch_bounds__(256, 3) void mid_k(Args a) {
    __shared__ __align__(16) unsigned char smem[SMEM_BYTES];
    WSP wsp = mkws(a.ws);
    if (blockIdx.x < 512) phase_flash(blockIdx.x, threadIdx.x, smem, a, wsp);
    else phase_gram(blockIdx.x - 512, threadIdx.x, smem, a, wsp);
}
__global__ __launch_bounds__(256, 3) void post_k(Args a) {
    __shared__ __align__(16) unsigned char smem[SMEM_BYTES];
    WSP wsp = mkws(a.ws);
    phase_post(blockIdx.x, threadIdx.x, smem, a, wsp);
}

extern "C" void kernel_launch(void* const* d_in, const int* in_sizes, int n_in,
                              void* d_out, int out_size, void* d_ws, size_t ws_size,
                              hipStream_t stream) {
    (void)in_sizes; (void)n_in; (void)out_size; (void)ws_size;
    Args a;
    a.U    = (const float*)d_in[0];
    a.Sg   = (const float*)d_in[1];
    a.Vagf = (const float*)d_in[2];
    a.vals = (const float*)d_in[3];
    a.Q    = (const float*)d_in[4];
    a.Ksm  = (const float*)d_in[5];
    a.Vsm  = (const float*)d_in[6];
    a.gam  = (const float*)d_in[7];
    a.ws   = (float*)d_ws;
    a.out  = (float*)d_out;

    void* kargs[] = {&a};
    hipError_t err = hipLaunchCooperativeKernel(fused, dim3(NBLK), dim3(256), kargs, 0, stream);
    if (err != hipSuccess) {
        (void)hipGetLastError();   // clear error state; use ordinary 3-kernel path
        prep_k<<<512, 256, 0, stream>>>(a);
        mid_k<<<NBLK, 256, 0, stream>>>(a);
        post_k<<<NBLK, 256, 0, stream>>>(a);
    }
}